// Round 14
// baseline (143.969 us; speedup 1.0000x reference)
//
#include <hip/hip_runtime.h>
#include <math.h>

#define NROWS 8192
#define DIM   1024
#define GRID  64          // 64x64 cells over [0,1)^2
#define CELLW 0.015625f   // 1/64
#define CAP   16          // bucket capacity per cell (max cell count ~12)
#define CAPSH 4

__device__ __forceinline__ int cell_of(float v) {
    int c = (int)(v * 64.0f);
    return c < 0 ? 0 : (c > 63 ? 63 : c);
}

// Emulated numpy-f32 squared distance (identical to the passing R4-R13 kernels).
__device__ __forceinline__ float np_d2(float xi, float yi, float sqi,
                                       float xj, float yj) {
    float sqj = __fadd_rn(__fmul_rn(xj, xj), __fmul_rn(yj, yj));
    float G   = fmaf(yi, yj, __fmul_rn(xi, xj));
    return __fsub_rn(__fadd_rn(sqi, sqj), __fmul_rn(2.0f, G));
}

// Kernel 1: bucket scatter (no sort, no scan) + row norms.
// cnt[] must be zeroed beforehand (hipMemsetAsync).
__global__ __launch_bounds__(256) void prep_kernel(
    const float* __restrict__ coords,
    const float* __restrict__ h0,
    int* __restrict__ cnt,          // 4096
    float4* __restrict__ buckets,   // 4096*CAP: (x, y, sq_np, idx_bits)
    float* __restrict__ norms) {    // 8192

    // ---- scatter (first 8192 global threads) ----
    int gid = blockIdx.x * 256 + threadIdx.x;
    if (gid < NROWS) {
        float2 c = ((const float2*)coords)[gid];
        int cell = cell_of(c.y) * GRID + cell_of(c.x);
        int pos = atomicAdd(cnt + cell, 1);
        if (pos < CAP) {
            float sq = __fadd_rn(__fmul_rn(c.x, c.x), __fmul_rn(c.y, c.y));
            buckets[(cell << CAPSH) + pos] =
                make_float4(c.x, c.y, sq, __int_as_float(gid));
        }
    }

    // ---- norms: 512 blocks x 4 waves x 4 rows (accumulation + ascending
    // butterfly chosen to bit-match the R13 self-dot path) ----
    const int wv   = threadIdx.x >> 6;
    const int lane = threadIdx.x & 63;
#pragma unroll
    for (int k = 0; k < 4; ++k) {
        int row = blockIdx.x * 16 + wv * 4 + k;
        const float4* hp = (const float4*)(h0 + (size_t)row * DIM);
        float acc = 0.f;
#pragma unroll
        for (int t = 0; t < 4; ++t) {
            float4 v = hp[lane + 64 * t];
            acc += v.x * v.x + v.y * v.y + v.z * v.z + v.w * v.w;
        }
#pragma unroll
        for (int off = 1; off < 64; off <<= 1) acc += __shfl_xor(acc, off, 64);
        if (lane == 0) norms[row] = sqrtf(acc);
    }
}

// Kernel 2: block-per-row mega kernel: knn (exact top-10, bit-identical keys
// and expansion rule) -> staged slot gather -> blend + MLP, all in one block.
__global__ __launch_bounds__(256) void mega_kernel(
    const float* __restrict__ coords,
    const int* __restrict__ cnt,
    const float4* __restrict__ buckets,
    const float* __restrict__ h0,
    const float* __restrict__ norms,
    const float* __restrict__ W1, const float* __restrict__ b1,
    const float* __restrict__ W2, const float* __restrict__ b2,
    float* __restrict__ out) {

    __shared__ unsigned long long wtop[4][10];
    __shared__ unsigned long long chosenLDS[10];
    __shared__ float prLDS[10];
    __shared__ int doneLDS;

    const int row  = blockIdx.x;
    const int t    = threadIdx.x;
    const int wv   = t >> 6;
    const int lane = t & 63;

    const float2 ci = ((const float2*)coords)[row];
    const float xi = ci.x, yi = ci.y;
    const float sqi = __fadd_rn(__fmul_rn(xi, xi), __fmul_rn(yi, yi));
    const int cx = cell_of(xi), cy = cell_of(yi);

    // ================= knn =================
    int C = 2;
    while (true) {
        unsigned long long best[10];
#pragma unroll
        for (int s = 0; s < 10; ++s) best[s] = ~0ULL;

        int x0 = max(0, cx - C), x1 = min(GRID - 1, cx + C);
        int y0 = max(0, cy - C), y1 = min(GRID - 1, cy + C);
        int rowCells = x1 - x0 + 1;

        for (int yy = y0; yy <= y1; ++yy) {
            int base = yy * GRID + x0;
            for (int li = t; li < (rowCells << CAPSH); li += 256) {
                int cell = base + (li >> CAPSH);
                int slot = li & (CAP - 1);
                int cn = cnt[cell]; cn = cn > CAP ? CAP : cn;
                if (slot < cn) {
                    float4 c = buckets[(cell << CAPSH) + slot];
                    float d2  = __fsub_rn(__fadd_rn(sqi, c.z),
                                  __fmul_rn(2.0f, fmaf(yi, c.y, __fmul_rn(xi, c.x))));
                    float dst = __fsqrt_rn(fmaxf(d2, 0.0f));
                    unsigned long long key =
                        ((unsigned long long)__float_as_uint(dst) << 32)
                        | (unsigned int)__float_as_int(c.w);
                    if (key < best[9]) {
                        best[9] = key;
#pragma unroll
                        for (int ss = 9; ss >= 1; --ss) {
                            unsigned long long a = best[ss - 1], b = best[ss];
                            unsigned long long lo = a < b ? a : b;
                            unsigned long long hi = a < b ? b : a;
                            best[ss - 1] = lo;
                            best[ss]     = hi;
                        }
                    }
                }
            }
        }

        // wave-level merge: 10 rounds of 64-lane head-min with pop
        unsigned long long merged[10];
#pragma unroll
        for (int r = 0; r < 10; ++r) {
            unsigned long long mn = best[0];
#pragma unroll
            for (int off = 1; off < 64; off <<= 1) {
                unsigned long long o = __shfl_xor(mn, off, 64);
                mn = (o < mn) ? o : mn;
            }
            if (best[0] == mn) {
#pragma unroll
                for (int ss = 0; ss < 9; ++ss) best[ss] = best[ss + 1];
                best[9] = ~0ULL;
            }
            merged[r] = mn;
        }
        if (lane == 0) {
#pragma unroll
            for (int r = 0; r < 10; ++r) wtop[wv][r] = merged[r];
        }
        __syncthreads();

        // wave 0: merge the 4 wave-lists (40 keys, one per lane)
        if (wv == 0) {
            unsigned long long mykey =
                (lane < 40) ? ((unsigned long long*)wtop)[lane] : ~0ULL;
#pragma unroll
            for (int r = 0; r < 10; ++r) {
                unsigned long long mn = mykey;
#pragma unroll
                for (int off = 1; off < 64; off <<= 1) {
                    unsigned long long o = __shfl_xor(mn, off, 64);
                    mn = (o < mn) ? o : mn;
                }
                if (mykey == mn) mykey = ~0ULL;
                if (lane == 0) chosenLDS[r] = mn;
            }
            if (lane == 0) {
                int done = 0;
                unsigned long long c9 = chosenLDS[9];
                if (c9 != ~0ULL) {
                    float d9 = __uint_as_float((unsigned int)(c9 >> 32));
                    if (d9 + 1.0e-3f <= (float)C * CELLW) done = 1;
                }
                if (C >= GRID) done = 1;
                doneLDS = done;
            }
        }
        __syncthreads();
        if (doneLDS) break;
        C <<= 1; if (C > GRID) C = GRID;
    }

    // ================= gather (R13 staged slots, pdot via LDS) =============
    unsigned long long ck[10];
#pragma unroll
    for (int r = 0; r < 10; ++r) ck[r] = chosenLDS[r];

    const float4* hi = (const float4*)(h0 + (size_t)row * DIM);
    const int s0 = wv, s1 = wv + 4, s2 = wv + 8;
    const bool nbr2 = (wv <= 1);

    const int j0 = (int)(ck[s0] & 0xFFFFFFFFu);
    const int j1 = (int)(ck[s1] & 0xFFFFFFFFu);
    const int j2 = nbr2 ? (int)(ck[s2] & 0xFFFFFFFFu) : 0;

    const float4* b0p = (const float4*)(h0 + (size_t)j0 * DIM);
    const float4* b1p = (const float4*)(h0 + (size_t)j1 * DIM);
    const float4* b2p = (const float4*)(h0 + (size_t)j2 * DIM);

    float4 av[4], bv0[4], bv1[4], bv2[4];
#pragma unroll
    for (int tt = 0; tt < 4; ++tt) {
        av[tt]  = hi [lane + 64 * tt];
        bv0[tt] = b0p[lane + 64 * tt];
        bv1[tt] = b1p[lane + 64 * tt];
    }
    if (nbr2) {
#pragma unroll
        for (int tt = 0; tt < 4; ++tt) bv2[tt] = b2p[lane + 64 * tt];
    }

    float p0 = 0.f, p1 = 0.f, p2 = 0.f;
#pragma unroll
    for (int tt = 0; tt < 4; ++tt) {
        p0 += av[tt].x * bv0[tt].x + av[tt].y * bv0[tt].y + av[tt].z * bv0[tt].z + av[tt].w * bv0[tt].w;
        p1 += av[tt].x * bv1[tt].x + av[tt].y * bv1[tt].y + av[tt].z * bv1[tt].z + av[tt].w * bv1[tt].w;
    }
    if (nbr2) {
#pragma unroll
        for (int tt = 0; tt < 4; ++tt)
            p2 += av[tt].x * bv2[tt].x + av[tt].y * bv2[tt].y + av[tt].z * bv2[tt].z + av[tt].w * bv2[tt].w;
    }

#pragma unroll
    for (int off = 1; off < 64; off <<= 1) {
        p0 += __shfl_xor(p0, off, 64);
        p1 += __shfl_xor(p1, off, 64);
        p2 += __shfl_xor(p2, off, 64);
    }
    if (lane == 0) {
        prLDS[s0] = p0;
        prLDS[s1] = p1;
        if (nbr2) prLDS[s2] = p2;
    }
    __syncthreads();

    if (wv != 0) return;

    // ================= final: blend + MLP (verbatim R5-R13 logic) ==========
    auto clamped_d2 = [&](unsigned long long key) -> float {
        int j = (int)(key & 0xFFFFFFFFu);
        float2 cj = ((const float2*)coords)[j];
        return fmaxf(np_d2(xi, yi, sqi, cj.x, cj.y), 0.0f);
    };
    const float m0 = clamped_d2(ck[0]);
    const float m1 = clamped_d2(ck[1]);
    const float m2 = clamped_d2(ck[2]);
    const float m8 = clamped_d2(ck[8]);
    const float m9 = clamped_d2(ck[9]);

    const float WIN = 2.0e-6f;
    const bool fpair = (m1 - m0) <= WIN;
    const bool ftri  = fpair && ((m2 - m0) <= WIN);
    const bool f89   = (m9 - m8) <= WIN;

    float wd[3];
    wd[0] = ftri ? (1.f / 3.f) : (fpair ? 0.5f : 1.0f);
    wd[1] = ftri ? (1.f / 3.f) : (fpair ? 0.5f : 0.0f);
    wd[2] = ftri ? (1.f / 3.f) : 0.0f;
    const float wc0 = f89 ? 0.5f : 1.0f;
    const float wc1 = f89 ? 0.5f : 0.0f;

    const float ni = fmaxf(norms[row], 1e-8f);

    float sim[10], sw[10];
#pragma unroll
    for (int r = 0; r < 10; ++r) {
        int   j   = (int)(ck[r] & 0xFFFFFFFFu);
        float dst = __uint_as_float((unsigned int)(ck[r] >> 32));
        float nj  = fmaxf(norms[j], 1e-8f);
        sim[r] = prLDS[r] / (ni * nj);
        sw[r]  = expf(__fdiv_rn(-dst, 0.05f));
    }

    float Ssim = 0.f, Ssw = 0.f;
#pragma unroll
    for (int r = 0; r < 9; ++r) { Ssim += sim[r]; Ssw += sw[r]; }

    const float w1a = W1[lane], w1b = W1[64 + lane];
    const float b1l = b1[lane], w2l = W2[lane], b2s = b2[0];

    float outacc = 0.f;
#pragma unroll
    for (int d = 0; d < 3; ++d) {
#pragma unroll
        for (int c = 0; c < 2; ++c) {
            float wgt = wd[d] * (c ? wc1 : wc0);
            float simsum = Ssim - sim[d] + (c ? (sim[9] - sim[8]) : 0.f);
            float swsum  = Ssw  - sw[d]  + (c ? (sw[9]  - sw[8])  : 0.f);
            float di0 = simsum * 0.125f;
            float di1 = swsum  * 0.125f;
            float hm = fmaxf(di0 * w1a + di1 * w1b + b1l, 0.f);
            float v  = hm * w2l;
#pragma unroll
            for (int off = 1; off < 64; off <<= 1) v += __shfl_xor(v, off, 64);
            float z = v + b2s;
            outacc += wgt * (1.f / (1.f + expf(-z)));
        }
    }

    if (lane == 0) out[row] = outacc;
}

extern "C" void kernel_launch(void* const* d_in, const int* in_sizes, int n_in,
                              void* d_out, int out_size, void* d_ws, size_t ws_size,
                              hipStream_t stream) {
    const float* h0     = (const float*)d_in[0];
    const float* coords = (const float*)d_in[1];
    const float* W1     = (const float*)d_in[2];
    const float* b1     = (const float*)d_in[3];
    const float* W2     = (const float*)d_in[4];
    const float* b2     = (const float*)d_in[5];
    float* out = (float*)d_out;

    // ws layout
    char* ws = (char*)d_ws;
    float4* buckets = (float4*)(ws);                 // 4096*16*16 = 1048576 B
    int*    cnt     = (int*)(ws + 1048576);          // 16384 B
    float*  norms   = (float*)(ws + 1064960);        // 32768 B

    hipMemsetAsync(cnt, 0, 4096 * sizeof(int), stream);
    prep_kernel<<<512, 256, 0, stream>>>(coords, h0, cnt, buckets, norms);
    mega_kernel<<<NROWS, 256, 0, stream>>>(coords, cnt, buckets, h0, norms,
                                           W1, b1, W2, b2, out);
}

// Round 15
// 80.035 us; speedup vs baseline: 1.7988x; 1.7988x over previous
//
#include <hip/hip_runtime.h>
#include <math.h>

#define NROWS 8192
#define DIM   1024
#define GRID  64          // 64x64 cells over [0,1)^2
#define CELLW 0.015625f   // 1/64
#define LPR   16          // lanes cooperating per row in knn
#define NCACHE 15         // LDS-cached unique neighbor rows per block

__device__ __forceinline__ int cell_of(float v) {
    int c = (int)(v * 64.0f);
    return c < 0 ? 0 : (c > 63 ? 63 : c);
}

// Emulated numpy-f32 squared distance (identical to the passing R4-R14 kernels).
__device__ __forceinline__ float np_d2(float xi, float yi, float sqi,
                                       float xj, float yj) {
    float sqj = __fadd_rn(__fmul_rn(xj, xj), __fmul_rn(yj, yj));
    float G   = fmaf(yi, yj, __fmul_rn(xi, xj));
    return __fsub_rn(__fadd_rn(sqi, sqj), __fmul_rn(2.0f, G));
}

// Row norms (accumulation + ascending butterfly, matching the passing chain).
__global__ __launch_bounds__(256) void norms_kernel(const float* __restrict__ h0,
                                                    float* __restrict__ norms) {
    int wave = (blockIdx.x * 256 + threadIdx.x) >> 6;
    int lane = threadIdx.x & 63;
    const float4* hp = (const float4*)(h0 + (size_t)wave * DIM);
    float acc = 0.f;
#pragma unroll
    for (int t = 0; t < 4; ++t) {
        float4 v = hp[lane + 64 * t];
        acc += v.x * v.x + v.y * v.y + v.z * v.z + v.w * v.w;
    }
#pragma unroll
    for (int off = 1; off < 64; off <<= 1) acc += __shfl_xor(acc, off, 64);
    if (lane == 0) norms[wave] = sqrtf(acc);
}

// Fused count + scan + scatter, one block (1024 threads), LDS-resident counts.
__global__ __launch_bounds__(1024) void build_grid_kernel(
    const float* __restrict__ coords,
    int* __restrict__ cellStart,     // 4097
    float4* __restrict__ sxyz) {     // 8192: (x, y, sq_np, idx_bits)

    __shared__ int lcnt[4096];
    __shared__ int wsum[16];
    const int t = threadIdx.x;

    for (int i = t; i < 4096; i += 1024) lcnt[i] = 0;
    __syncthreads();

    float2 pc[8]; int pcell[8];
#pragma unroll
    for (int k = 0; k < 8; ++k) {
        int i = t + 1024 * k;
        float2 c = ((const float2*)coords)[i];
        pc[k] = c;
        pcell[k] = cell_of(c.y) * GRID + cell_of(c.x);
        atomicAdd(&lcnt[pcell[k]], 1);
    }
    __syncthreads();

    int c0 = lcnt[t*4+0], c1 = lcnt[t*4+1], c2 = lcnt[t*4+2], c3 = lcnt[t*4+3];
    int s1 = c0, s2 = c0 + c1, s3 = s2 + c2, s4 = s3 + c3;
    int lane = t & 63, wid = t >> 6;
    int inc = s4;
#pragma unroll
    for (int off = 1; off < 64; off <<= 1) {
        int o = __shfl_up(inc, off, 64);
        if (lane >= off) inc += o;
    }
    if (lane == 63) wsum[wid] = inc;
    __syncthreads();
    int wbase = 0;
    for (int w = 0; w < wid; ++w) wbase += wsum[w];
    int excl = wbase + inc - s4;

    cellStart[t*4+0] = excl;
    cellStart[t*4+1] = excl + s1;
    cellStart[t*4+2] = excl + s2;
    cellStart[t*4+3] = excl + s3;
    if (t == 1023) cellStart[4096] = excl + s4;
    lcnt[t*4+0] = excl;
    lcnt[t*4+1] = excl + s1;
    lcnt[t*4+2] = excl + s2;
    lcnt[t*4+3] = excl + s3;
    __syncthreads();

#pragma unroll
    for (int k = 0; k < 8; ++k) {
        int pos = atomicAdd(&lcnt[pcell[k]], 1);
        float x = pc[k].x, y = pc[k].y;
        float sq = __fadd_rn(__fmul_rn(x, x), __fmul_rn(y, y));
        sxyz[pos] = make_float4(x, y, sq, __int_as_float(t + 1024 * k));
    }
}

// Phase 1: exact top-10 of (np-f32 dist, index) per row. 16 lanes per row.
__global__ __launch_bounds__(256) void knn_kernel(
    const int* __restrict__ cellStart,
    const float4* __restrict__ sxyz,
    unsigned long long* __restrict__ chosen_ws) {

    const int sub = threadIdx.x & (LPR - 1);
    const int g   = (blockIdx.x * 256 + threadIdx.x) / LPR;

    const float4 me = sxyz[g];
    const float xi = me.x, yi = me.y, sqi = me.z;
    const int row = __float_as_int(me.w);
    const int cx = cell_of(xi), cy = cell_of(yi);

    unsigned long long best[10], merged[10];
    int C = 2;
    while (true) {
#pragma unroll
        for (int s = 0; s < 10; ++s) best[s] = ~0ULL;
        int x0 = max(0, cx - C), x1 = min(GRID - 1, cx + C);
        int y0 = max(0, cy - C), y1 = min(GRID - 1, cy + C);
        for (int yy = y0; yy <= y1; ++yy) {
            int s = cellStart[yy * GRID + x0];
            int e = cellStart[yy * GRID + x1 + 1];
            for (int t = s + sub; t < e; t += LPR) {
                float4 c = sxyz[t];
                float d2  = __fsub_rn(__fadd_rn(sqi, c.z),
                                      __fmul_rn(2.0f, fmaf(yi, c.y, __fmul_rn(xi, c.x))));
                float dst = __fsqrt_rn(fmaxf(d2, 0.0f));
                unsigned long long key =
                    ((unsigned long long)__float_as_uint(dst) << 32)
                    | (unsigned int)__float_as_int(c.w);
                if (key < best[9]) {
                    best[9] = key;
#pragma unroll
                    for (int ss = 9; ss >= 1; --ss) {
                        unsigned long long a = best[ss - 1], b = best[ss];
                        unsigned long long lo = a < b ? a : b;
                        unsigned long long hi = a < b ? b : a;
                        best[ss - 1] = lo;
                        best[ss]     = hi;
                    }
                }
            }
        }
#pragma unroll
        for (int r = 0; r < 10; ++r) {
            unsigned long long mn = best[0];
#pragma unroll
            for (int off = 1; off < LPR; off <<= 1) {
                unsigned long long o = __shfl_xor(mn, off, 64);
                mn = (o < mn) ? o : mn;
            }
            if (best[0] == mn) {
#pragma unroll
                for (int ss = 0; ss < 9; ++ss) best[ss] = best[ss + 1];
                best[9] = ~0ULL;
            }
            merged[r] = mn;
        }
        bool done = false;
        if (merged[9] != ~0ULL) {
            float d9 = __uint_as_float((unsigned int)(merged[9] >> 32));
            if (d9 + 1.0e-3f <= (float)C * CELLW) done = true;
        }
        if (done || C >= GRID) break;
        C <<= 1; if (C > GRID) C = GRID;
    }

    if (sub == 0) {
        unsigned long long* o = chosen_ws + (size_t)row * 10;
#pragma unroll
        for (int r = 0; r < 10; ++r) o[r] = merged[r];
    }
}

// Phase 2: 4 consecutive sorted rows per block (wave-per-row). Wave 0 dedupes
// the 40 neighbor ids; block caches <=NCACHE unique rows in LDS once; waves
// compute dots from LDS (overflow slots -> direct global). Blend+MLP in-wave.
__global__ __launch_bounds__(256) void gather_final_kernel(
    const float* __restrict__ h0,
    const float* __restrict__ coords,
    const unsigned long long* __restrict__ chosen_ws,
    const float4* __restrict__ sxyz,
    const float* __restrict__ norms,
    const float* __restrict__ W1, const float* __restrict__ b1,
    const float* __restrict__ W2, const float* __restrict__ b2,
    float* __restrict__ out) {

    __shared__ float ldsRows[NCACHE][DIM];          // 61440 B
    __shared__ unsigned long long chLDS[40];
    __shared__ int slotSrc[40];
    __shared__ int uniq[NCACHE];
    __shared__ int ridLDS[4];

    const int t    = threadIdx.x;
    const int wv   = t >> 6;
    const int lane = t & 63;
    const int bid  = blockIdx.x;
    const int grp  = (bid & 7) * (gridDim.x / 8) + (bid >> 3);  // XCD-chunked

    // ---- wave 0: load group rows' ids + chosen lists, dedupe ----
    if (wv == 0) {
        if (lane < 4) ridLDS[lane] = __float_as_int(sxyz[grp * 4 + lane].w);
        int rid4 = __shfl(ridLDS[0], 0, 64);  // ensure visibility via shfl? no-
        (void)rid4;
        // all lanes need ridLDS written before use; wave-coherent LDS: use
        // s_waitcnt via barrier-free same-wave access (LDS writes from lanes
        // 0-3 are visible to the wave after the implicit lgkmcnt wait).
        unsigned long long mykey = ~0ULL;
        int myid = -1;
        if (lane < 40) {
            int r = ridLDS[lane / 10];          // same-wave LDS read
            mykey = chosen_ws[(size_t)r * 10 + (lane % 10)];
            myid  = (int)(mykey & 0xFFFFFFFFu);
            chLDS[lane] = mykey;
        }
        int dupof = -1;
#pragma unroll 8
        for (int m = 0; m < 40; ++m) {
            int idm = __shfl(myid, m, 64);
            if (dupof < 0 && m < lane && idm == myid) dupof = m;
        }
        bool isuniq = (lane < 40) && (dupof < 0);
        unsigned long long um = __ballot(isuniq);
        int upos = __popcll(um & ((1ULL << lane) - 1ULL));
        int srcLane = (dupof < 0) ? lane : dupof;
        int gotPos  = __shfl(upos, srcLane, 64);
        if (lane < 40) slotSrc[lane] = (gotPos < NCACHE) ? gotPos : -1;
        if (isuniq && upos < NCACHE) uniq[upos] = myid;
        if (lane == 0) {
            int U = (int)__popcll(um);
            uniq[0] = (upos == 0 && isuniq) ? myid : uniq[0]; // no-op guard
            slotSrc[0] = slotSrc[0];                          // keep
            // store U in uniq slot? use a dedicated location:
        }
        // store count in chLDS tail? use slotSrc spare: none. Use static:
    }
    __syncthreads();

    // recompute nU from slotSrc-independent source: count uniques via uniq[]
    // is unsafe; derive from slotSrc max+1:
    int nU = 0;
#pragma unroll
    for (int k = 0; k < 40; ++k) nU = max(nU, slotSrc[k] + 1);

    // ---- cooperative LDS fill ----
    for (int u = 0; u < nU; ++u) {
        const float4* src = (const float4*)(h0 + (size_t)uniq[u] * DIM);
        ((float4*)ldsRows[u])[t] = src[t];
    }
    __syncthreads();

    // ---- per-wave: row dots ----
    const int row = ridLDS[wv];
    unsigned long long ck[10];
#pragma unroll
    for (int r = 0; r < 10; ++r) ck[r] = chLDS[wv * 10 + r];

    const float4* hi = (const float4*)(h0 + (size_t)row * DIM);
    float4 av[4];
#pragma unroll
    for (int tt = 0; tt < 4; ++tt) av[tt] = hi[lane + 64 * tt];

    float p[10];
#pragma unroll
    for (int s = 0; s < 10; ++s) {
        int src = slotSrc[wv * 10 + s];
        float ps = 0.f;
        if (src >= 0) {
            const float4* bp = (const float4*)ldsRows[src];
#pragma unroll
            for (int tt = 0; tt < 4; ++tt) {
                float4 b = bp[lane + 64 * tt];
                ps += av[tt].x * b.x + av[tt].y * b.y + av[tt].z * b.z + av[tt].w * b.w;
            }
        } else {
            int j = (int)(ck[s] & 0xFFFFFFFFu);
            const float4* bp = (const float4*)(h0 + (size_t)j * DIM);
#pragma unroll
            for (int tt = 0; tt < 4; ++tt) {
                float4 b = bp[lane + 64 * tt];
                ps += av[tt].x * b.x + av[tt].y * b.y + av[tt].z * b.z + av[tt].w * b.w;
            }
        }
        p[s] = ps;
    }

#pragma unroll
    for (int s = 0; s < 10; ++s) {
        float v = p[s];
#pragma unroll
        for (int off = 1; off < 64; off <<= 1) v += __shfl_xor(v, off, 64);
        p[s] = v;
    }

    // ---- blend flags + sim/sw + MLP (verbatim from R10, which passed) ----
    const float2 ci = ((const float2*)coords)[row];
    const float xi = ci.x, yi = ci.y;
    const float sqi = __fadd_rn(__fmul_rn(xi, xi), __fmul_rn(yi, yi));

    auto clamped_d2 = [&](unsigned long long key) -> float {
        int j = (int)(key & 0xFFFFFFFFu);
        float2 cj = ((const float2*)coords)[j];
        return fmaxf(np_d2(xi, yi, sqi, cj.x, cj.y), 0.0f);
    };
    const float m0 = clamped_d2(ck[0]);
    const float m1 = clamped_d2(ck[1]);
    const float m2 = clamped_d2(ck[2]);
    const float m8 = clamped_d2(ck[8]);
    const float m9 = clamped_d2(ck[9]);

    const float WIN = 2.0e-6f;
    const bool fpair = (m1 - m0) <= WIN;
    const bool ftri  = fpair && ((m2 - m0) <= WIN);
    const bool f89   = (m9 - m8) <= WIN;

    float wd[3];
    wd[0] = ftri ? (1.f / 3.f) : (fpair ? 0.5f : 1.0f);
    wd[1] = ftri ? (1.f / 3.f) : (fpair ? 0.5f : 0.0f);
    wd[2] = ftri ? (1.f / 3.f) : 0.0f;
    const float wc0 = f89 ? 0.5f : 1.0f;
    const float wc1 = f89 ? 0.5f : 0.0f;

    const float ni = fmaxf(norms[row], 1e-8f);

    float sim[10], sw[10];
#pragma unroll
    for (int r = 0; r < 10; ++r) {
        int   j   = (int)(ck[r] & 0xFFFFFFFFu);
        float dst = __uint_as_float((unsigned int)(ck[r] >> 32));
        float nj  = fmaxf(norms[j], 1e-8f);
        sim[r] = p[r] / (ni * nj);
        sw[r]  = expf(__fdiv_rn(-dst, 0.05f));
    }

    float Ssim = 0.f, Ssw = 0.f;
#pragma unroll
    for (int r = 0; r < 9; ++r) { Ssim += sim[r]; Ssw += sw[r]; }

    const float w1a = W1[lane], w1b = W1[64 + lane];
    const float b1l = b1[lane], w2l = W2[lane], b2s = b2[0];

    float outacc = 0.f;
#pragma unroll
    for (int d = 0; d < 3; ++d) {
#pragma unroll
        for (int c = 0; c < 2; ++c) {
            float wgt = wd[d] * (c ? wc1 : wc0);
            float simsum = Ssim - sim[d] + (c ? (sim[9] - sim[8]) : 0.f);
            float swsum  = Ssw  - sw[d]  + (c ? (sw[9]  - sw[8])  : 0.f);
            float di0 = simsum * 0.125f;
            float di1 = swsum  * 0.125f;
            float hm = fmaxf(di0 * w1a + di1 * w1b + b1l, 0.f);
            float v  = hm * w2l;
#pragma unroll
            for (int off = 1; off < 64; off <<= 1) v += __shfl_xor(v, off, 64);
            float z = v + b2s;
            outacc += wgt * (1.f / (1.f + expf(-z)));
        }
    }

    if (lane == 0) out[row] = outacc;
}

extern "C" void kernel_launch(void* const* d_in, const int* in_sizes, int n_in,
                              void* d_out, int out_size, void* d_ws, size_t ws_size,
                              hipStream_t stream) {
    const float* h0     = (const float*)d_in[0];
    const float* coords = (const float*)d_in[1];
    const float* W1     = (const float*)d_in[2];
    const float* b1     = (const float*)d_in[3];
    const float* W2     = (const float*)d_in[4];
    const float* b2     = (const float*)d_in[5];
    float* out = (float*)d_out;

    char* ws = (char*)d_ws;
    unsigned long long* chosen_ws = (unsigned long long*)(ws);    // 655360 B
    float*  norms     = (float*)(ws + 655360);                    //  32768 B
    float4* sxyz      = (float4*)(ws + 1015808);                  // 131072 B
    int*    cellStart = (int*)(ws + 1146880);                     //  16388 B

    build_grid_kernel  <<<1, 1024, 0, stream>>>(coords, cellStart, sxyz);
    knn_kernel         <<<NROWS * LPR / 256, 256, 0, stream>>>(cellStart, sxyz, chosen_ws);
    norms_kernel       <<<NROWS / 4, 256, 0, stream>>>(h0, norms);
    gather_final_kernel<<<NROWS / 4, 256, 0, stream>>>(h0, coords, chosen_ws, sxyz,
                                                       norms, W1, b1, W2, b2, out);
}

// Round 16
// 67.069 us; speedup vs baseline: 2.1466x; 1.1933x over previous
//
#include <hip/hip_runtime.h>
#include <math.h>

#define NROWS 8192
#define DIM   1024
#define GRID  64          // 64x64 cells over [0,1)^2
#define CELLW 0.015625f   // 1/64
#define LPR   16          // lanes cooperating per row in knn

__device__ __forceinline__ int cell_of(float v) {
    int c = (int)(v * 64.0f);
    return c < 0 ? 0 : (c > 63 ? 63 : c);
}

// Emulated numpy-f32 squared distance (identical to the passing R4-R15 kernels).
__device__ __forceinline__ float np_d2(float xi, float yi, float sqi,
                                       float xj, float yj) {
    float sqj = __fadd_rn(__fmul_rn(xj, xj), __fmul_rn(yj, yj));
    float G   = fmaf(yi, yj, __fmul_rn(xi, xj));
    return __fsub_rn(__fadd_rn(sqi, sqj), __fmul_rn(2.0f, G));
}

__global__ __launch_bounds__(256) void count_kernel(const float* __restrict__ coords,
                                                    int* __restrict__ cnt) {
    int i = blockIdx.x * 256 + threadIdx.x;
    float2 c = ((const float2*)coords)[i];
    atomicAdd(cnt + cell_of(c.y) * GRID + cell_of(c.x), 1);
}

__global__ __launch_bounds__(1024) void scan_kernel(const int* __restrict__ cnt,
                                                    int* __restrict__ start,
                                                    int* __restrict__ cur) {
    __shared__ int wsum[16];
    int t = threadIdx.x;                 // 0..1023, 4 cells each
    int c0 = cnt[t * 4 + 0], c1 = cnt[t * 4 + 1], c2 = cnt[t * 4 + 2], c3 = cnt[t * 4 + 3];
    int s1 = c0, s2 = c0 + c1, s3 = s2 + c2, s4 = s3 + c3;
    int lane = t & 63, wid = t >> 6;
    int inc = s4;
#pragma unroll
    for (int off = 1; off < 64; off <<= 1) {
        int o = __shfl_up(inc, off, 64);
        if (lane >= off) inc += o;
    }
    if (lane == 63) wsum[wid] = inc;
    __syncthreads();
    int wbase = 0;
    for (int w = 0; w < wid; ++w) wbase += wsum[w];
    int excl = wbase + inc - s4;
    start[t * 4 + 0] = excl;        cur[t * 4 + 0] = excl;
    start[t * 4 + 1] = excl + s1;   cur[t * 4 + 1] = excl + s1;
    start[t * 4 + 2] = excl + s2;   cur[t * 4 + 2] = excl + s2;
    start[t * 4 + 3] = excl + s3;   cur[t * 4 + 3] = excl + s3;
    if (t == 1023) start[4096] = excl + s4;
}

__global__ __launch_bounds__(256) void scatter_kernel(const float* __restrict__ coords,
                                                      int* __restrict__ cur,
                                                      float4* __restrict__ sxyz) {
    int i = blockIdx.x * 256 + threadIdx.x;
    float2 c = ((const float2*)coords)[i];
    int cell = cell_of(c.y) * GRID + cell_of(c.x);
    int pos = atomicAdd(cur + cell, 1);
    float sq = __fadd_rn(__fmul_rn(c.x, c.x), __fmul_rn(c.y, c.y));
    sxyz[pos] = make_float4(c.x, c.y, sq, __int_as_float(i));
}

// Phase 1: exact top-10 of (np-f32 dist, index) per row. 16 lanes per row.
__global__ __launch_bounds__(256) void knn_kernel(
    const int* __restrict__ cellStart,   // 4097
    const float4* __restrict__ sxyz,     // 8192
    unsigned long long* __restrict__ chosen_ws) {

    const int sub = threadIdx.x & (LPR - 1);
    const int g   = (blockIdx.x * 256 + threadIdx.x) / LPR;   // sorted position

    const float4 me = sxyz[g];
    const float xi = me.x, yi = me.y, sqi = me.z;
    const int row = __float_as_int(me.w);
    const int cx = cell_of(xi), cy = cell_of(yi);

    unsigned long long best[10], merged[10];
    int C = 2;
    while (true) {
#pragma unroll
        for (int s = 0; s < 10; ++s) best[s] = ~0ULL;
        int x0 = max(0, cx - C), x1 = min(GRID - 1, cx + C);
        int y0 = max(0, cy - C), y1 = min(GRID - 1, cy + C);
        for (int yy = y0; yy <= y1; ++yy) {
            int s = cellStart[yy * GRID + x0];
            int e = cellStart[yy * GRID + x1 + 1];
            for (int t = s + sub; t < e; t += LPR) {
                float4 c = sxyz[t];
                float d2  = __fsub_rn(__fadd_rn(sqi, c.z),
                                      __fmul_rn(2.0f, fmaf(yi, c.y, __fmul_rn(xi, c.x))));
                float dst = __fsqrt_rn(fmaxf(d2, 0.0f));
                unsigned long long key =
                    ((unsigned long long)__float_as_uint(dst) << 32)
                    | (unsigned int)__float_as_int(c.w);
                if (key < best[9]) {
                    best[9] = key;
#pragma unroll
                    for (int ss = 9; ss >= 1; --ss) {
                        unsigned long long a = best[ss - 1], b = best[ss];
                        unsigned long long lo = a < b ? a : b;
                        unsigned long long hi = a < b ? b : a;
                        best[ss - 1] = lo;
                        best[ss]     = hi;
                    }
                }
            }
        }
        // merge 16 sorted lists: 10 rounds of head-min; winner pops its head
#pragma unroll
        for (int r = 0; r < 10; ++r) {
            unsigned long long mn = best[0];
#pragma unroll
            for (int off = 1; off < LPR; off <<= 1) {
                unsigned long long o = __shfl_xor(mn, off, 64);
                mn = (o < mn) ? o : mn;
            }
            if (best[0] == mn) {
#pragma unroll
                for (int ss = 0; ss < 9; ++ss) best[ss] = best[ss + 1];
                best[9] = ~0ULL;
            }
            merged[r] = mn;
        }
        bool done = false;
        if (merged[9] != ~0ULL) {
            float d9 = __uint_as_float((unsigned int)(merged[9] >> 32));
            if (d9 + 1.0e-3f <= (float)C * CELLW) done = true;
        }
        if (done || C >= GRID) break;
        C <<= 1; if (C > GRID) C = GRID;
    }

    if (sub == 0) {
        unsigned long long* o = chosen_ws + (size_t)row * 10;
#pragma unroll
        for (int r = 0; r < 10; ++r) o[r] = merged[r];
    }
}

// Phase 2: block-per-row, slot-per-wave with bounded up-front staging.
// wave0:{0,4,8} wave1:{1,5,9} wave2:{2,6,self} wave3:{3,7}.
__global__ __launch_bounds__(256) void gather_kernel(
    const float* __restrict__ h0,
    const unsigned long long* __restrict__ chosen_ws,
    const float4* __restrict__ sxyz,
    float* __restrict__ pdot,    // [NROWS][10]
    float* __restrict__ norms) { // [NROWS]

    const int wid  = threadIdx.x >> 6;
    const int lane = threadIdx.x & 63;
    const int bid  = blockIdx.x;
    const int grp  = (bid & 7) * (NROWS / 8) + (bid >> 3);  // XCD-chunked
    const int row  = __float_as_int(sxyz[grp].w);

    const unsigned long long* ch = chosen_ws + (size_t)row * 10;
    const float4* hi = (const float4*)(h0 + (size_t)row * DIM);

    const int s0 = wid, s1 = wid + 4, s2 = wid + 8;
    const bool nbr2  = (wid <= 1);   // slots 8,9 are neighbors
    const bool self2 = (wid == 2);   // slot 10 = self dot

    const int j0 = (int)(ch[s0] & 0xFFFFFFFFu);
    const int j1 = (int)(ch[s1] & 0xFFFFFFFFu);
    const int j2 = nbr2 ? (int)(ch[s2] & 0xFFFFFFFFu) : 0;

    const float4* b0p = (const float4*)(h0 + (size_t)j0 * DIM);
    const float4* b1p = (const float4*)(h0 + (size_t)j1 * DIM);
    const float4* b2p = (const float4*)(h0 + (size_t)j2 * DIM);

    float4 av[4], bv0[4], bv1[4], bv2[4];
#pragma unroll
    for (int t = 0; t < 4; ++t) {
        av[t]  = hi [lane + 64 * t];
        bv0[t] = b0p[lane + 64 * t];
        bv1[t] = b1p[lane + 64 * t];
    }
    if (nbr2) {
#pragma unroll
        for (int t = 0; t < 4; ++t) bv2[t] = b2p[lane + 64 * t];
    }

    float p0 = 0.f, p1 = 0.f, p2 = 0.f;
#pragma unroll
    for (int t = 0; t < 4; ++t) {
        p0 += av[t].x * bv0[t].x + av[t].y * bv0[t].y + av[t].z * bv0[t].z + av[t].w * bv0[t].w;
        p1 += av[t].x * bv1[t].x + av[t].y * bv1[t].y + av[t].z * bv1[t].z + av[t].w * bv1[t].w;
    }
    if (nbr2) {
#pragma unroll
        for (int t = 0; t < 4; ++t)
            p2 += av[t].x * bv2[t].x + av[t].y * bv2[t].y + av[t].z * bv2[t].z + av[t].w * bv2[t].w;
    } else if (self2) {
#pragma unroll
        for (int t = 0; t < 4; ++t)
            p2 += av[t].x * av[t].x + av[t].y * av[t].y + av[t].z * av[t].z + av[t].w * av[t].w;
    }

#pragma unroll
    for (int off = 1; off < 64; off <<= 1) {
        p0 += __shfl_xor(p0, off, 64);
        p1 += __shfl_xor(p1, off, 64);
        p2 += __shfl_xor(p2, off, 64);
    }

    if (lane == 0) {
        float* pr = pdot + (size_t)row * 10;
        pr[s0] = p0;
        pr[s1] = p1;
        if (nbr2)  pr[s2] = p2;
        if (self2) norms[row] = sqrtf(p2);
    }
}

// Phase 3: blend flags + sim/sw + MLP (verbatim from the passing chain)
__global__ __launch_bounds__(256) void final_kernel(
    const float* __restrict__ coords,
    const unsigned long long* __restrict__ chosen_ws,
    const float* __restrict__ pdot,
    const float* __restrict__ norms,
    const float* __restrict__ W1, const float* __restrict__ b1,
    const float* __restrict__ W2, const float* __restrict__ b2,
    float* __restrict__ out) {

    const int widx = threadIdx.x >> 6;
    const int lane = threadIdx.x & 63;
    const int row  = blockIdx.x * 4 + widx;

    const float2 ci = ((const float2*)coords)[row];
    const float xi = ci.x, yi = ci.y;
    const float sqi = __fadd_rn(__fmul_rn(xi, xi), __fmul_rn(yi, yi));

    unsigned long long chosen[10];
    const unsigned long long* ch = chosen_ws + (size_t)row * 10;
#pragma unroll
    for (int r = 0; r < 10; ++r) chosen[r] = ch[r];

    auto clamped_d2 = [&](unsigned long long key) -> float {
        int j = (int)(key & 0xFFFFFFFFu);
        float2 cj = ((const float2*)coords)[j];
        return fmaxf(np_d2(xi, yi, sqi, cj.x, cj.y), 0.0f);
    };
    const float m0 = clamped_d2(chosen[0]);
    const float m1 = clamped_d2(chosen[1]);
    const float m2 = clamped_d2(chosen[2]);
    const float m8 = clamped_d2(chosen[8]);
    const float m9 = clamped_d2(chosen[9]);

    const float WIN = 2.0e-6f;
    const bool fpair = (m1 - m0) <= WIN;
    const bool ftri  = fpair && ((m2 - m0) <= WIN);
    const bool f89   = (m9 - m8) <= WIN;

    float wd[3];
    wd[0] = ftri ? (1.f / 3.f) : (fpair ? 0.5f : 1.0f);
    wd[1] = ftri ? (1.f / 3.f) : (fpair ? 0.5f : 0.0f);
    wd[2] = ftri ? (1.f / 3.f) : 0.0f;
    const float wc0 = f89 ? 0.5f : 1.0f;
    const float wc1 = f89 ? 0.5f : 0.0f;

    const float ni = fmaxf(norms[row], 1e-8f);

    float sim[10], sw[10];
#pragma unroll
    for (int r = 0; r < 10; ++r) {
        int   j   = (int)(chosen[r] & 0xFFFFFFFFu);
        float dst = __uint_as_float((unsigned int)(chosen[r] >> 32));
        float nj  = fmaxf(norms[j], 1e-8f);
        sim[r] = pdot[(size_t)row * 10 + r] / (ni * nj);
        sw[r]  = expf(__fdiv_rn(-dst, 0.05f));
    }

    float Ssim = 0.f, Ssw = 0.f;
#pragma unroll
    for (int r = 0; r < 9; ++r) { Ssim += sim[r]; Ssw += sw[r]; }

    const float w1a = W1[lane], w1b = W1[64 + lane];
    const float b1l = b1[lane], w2l = W2[lane], b2s = b2[0];

    float outacc = 0.f;
#pragma unroll
    for (int d = 0; d < 3; ++d) {
#pragma unroll
        for (int c = 0; c < 2; ++c) {
            float wgt = wd[d] * (c ? wc1 : wc0);
            float simsum = Ssim - sim[d] + (c ? (sim[9] - sim[8]) : 0.f);
            float swsum  = Ssw  - sw[d]  + (c ? (sw[9]  - sw[8])  : 0.f);
            float di0 = simsum * 0.125f;
            float di1 = swsum  * 0.125f;
            float hm = fmaxf(di0 * w1a + di1 * w1b + b1l, 0.f);
            float v  = hm * w2l;
#pragma unroll
            for (int off = 1; off < 64; off <<= 1) v += __shfl_xor(v, off, 64);
            float z = v + b2s;
            outacc += wgt * (1.f / (1.f + expf(-z)));
        }
    }

    if (lane == 0) out[row] = outacc;
}

extern "C" void kernel_launch(void* const* d_in, const int* in_sizes, int n_in,
                              void* d_out, int out_size, void* d_ws, size_t ws_size,
                              hipStream_t stream) {
    const float* h0     = (const float*)d_in[0];
    const float* coords = (const float*)d_in[1];
    const float* W1     = (const float*)d_in[2];
    const float* b1     = (const float*)d_in[3];
    const float* W2     = (const float*)d_in[4];
    const float* b2     = (const float*)d_in[5];
    float* out = (float*)d_out;

    // ws layout
    char* ws = (char*)d_ws;
    unsigned long long* chosen_ws = (unsigned long long*)(ws);    // 655360 B
    float*  pdot      = (float*)(ws + 655360);                    // 327680 B
    float*  norms     = (float*)(ws + 983040);                    //  32768 B
    float4* sxyz      = (float4*)(ws + 1015808);                  // 131072 B
    int*    cellStart = (int*)(ws + 1146880);                     //  16388 B
    int*    cellCnt   = (int*)(ws + 1163268);                     //  16384 B
    int*    cellCur   = (int*)(ws + 1179652);                     //  16384 B

    hipMemsetAsync(cellCnt, 0, 4096 * sizeof(int), stream);
    count_kernel  <<<NROWS / 256, 256, 0, stream>>>(coords, cellCnt);
    scan_kernel   <<<1, 1024, 0, stream>>>(cellCnt, cellStart, cellCur);
    scatter_kernel<<<NROWS / 256, 256, 0, stream>>>(coords, cellCur, sxyz);
    knn_kernel    <<<NROWS * LPR / 256, 256, 0, stream>>>(cellStart, sxyz, chosen_ws);
    gather_kernel <<<NROWS, 256, 0, stream>>>(h0, chosen_ws, sxyz, pdot, norms);
    final_kernel  <<<NROWS / 4, 256, 0, stream>>>(coords, chosen_ws, pdot, norms,
                                                  W1, b1, W2, b2, out);
}

// Round 17
// 61.535 us; speedup vs baseline: 2.3396x; 1.0899x over previous
//
#include <hip/hip_runtime.h>
#include <math.h>

#define NROWS 8192
#define DIM   1024
#define GRID  64          // 64x64 cells over [0,1)^2
#define CELLW 0.015625f   // 1/64
#define LPR   8           // lanes cooperating per row in knn

__device__ __forceinline__ int cell_of(float v) {
    int c = (int)(v * 64.0f);
    return c < 0 ? 0 : (c > 63 ? 63 : c);
}

// Emulated numpy-f32 squared distance (identical to the passing R4-R16 kernels).
__device__ __forceinline__ float np_d2(float xi, float yi, float sqi,
                                       float xj, float yj) {
    float sqj = __fadd_rn(__fmul_rn(xj, xj), __fmul_rn(yj, yj));
    float G   = fmaf(yi, yj, __fmul_rn(xi, xj));
    return __fsub_rn(__fadd_rn(sqi, sqj), __fmul_rn(2.0f, G));
}

// Fused count + scan + scatter, one block (1024 threads), LDS-resident counts.
__global__ __launch_bounds__(1024) void build_grid_kernel(
    const float* __restrict__ coords,
    int* __restrict__ cellStart,     // 4097
    float4* __restrict__ sxyz) {     // 8192: (x, y, sq_np, idx_bits)

    __shared__ int lcnt[4096];
    __shared__ int wsum[16];
    const int t = threadIdx.x;

    for (int i = t; i < 4096; i += 1024) lcnt[i] = 0;
    __syncthreads();

    float2 pc[8]; int pcell[8];
#pragma unroll
    for (int k = 0; k < 8; ++k) {
        int i = t + 1024 * k;
        float2 c = ((const float2*)coords)[i];
        pc[k] = c;
        pcell[k] = cell_of(c.y) * GRID + cell_of(c.x);
        atomicAdd(&lcnt[pcell[k]], 1);
    }
    __syncthreads();

    // exclusive scan of 4096 counts, 4 cells per thread
    int c0 = lcnt[t*4+0], c1 = lcnt[t*4+1], c2 = lcnt[t*4+2], c3 = lcnt[t*4+3];
    int s1 = c0, s2 = c0 + c1, s3 = s2 + c2, s4 = s3 + c3;
    int lane = t & 63, wid = t >> 6;
    int inc = s4;
#pragma unroll
    for (int off = 1; off < 64; off <<= 1) {
        int o = __shfl_up(inc, off, 64);
        if (lane >= off) inc += o;
    }
    if (lane == 63) wsum[wid] = inc;
    __syncthreads();
    int wbase = 0;
    for (int w = 0; w < wid; ++w) wbase += wsum[w];
    int excl = wbase + inc - s4;

    cellStart[t*4+0] = excl;
    cellStart[t*4+1] = excl + s1;
    cellStart[t*4+2] = excl + s2;
    cellStart[t*4+3] = excl + s3;
    if (t == 1023) cellStart[4096] = excl + s4;
    lcnt[t*4+0] = excl;          // reuse as running cursor
    lcnt[t*4+1] = excl + s1;
    lcnt[t*4+2] = excl + s2;
    lcnt[t*4+3] = excl + s3;
    __syncthreads();

#pragma unroll
    for (int k = 0; k < 8; ++k) {
        int pos = atomicAdd(&lcnt[pcell[k]], 1);
        float x = pc[k].x, y = pc[k].y;
        float sq = __fadd_rn(__fmul_rn(x, x), __fmul_rn(y, y));
        sxyz[pos] = make_float4(x, y, sq, __int_as_float(t + 1024 * k));
    }
}

// Phase 1: exact top-10 of (np-f32 dist, index) per row. 8 lanes per row.
__global__ __launch_bounds__(256) void knn_kernel(
    const int* __restrict__ cellStart,   // 4097
    const float4* __restrict__ sxyz,     // 8192
    unsigned long long* __restrict__ chosen_ws) {

    const int sub = threadIdx.x & (LPR - 1);
    const int g   = (blockIdx.x * 256 + threadIdx.x) / LPR;   // sorted position

    const float4 me = sxyz[g];
    const float xi = me.x, yi = me.y, sqi = me.z;
    const int row = __float_as_int(me.w);
    const int cx = cell_of(xi), cy = cell_of(yi);

    unsigned long long best[10], merged[10];
    int C = 2;
    while (true) {
#pragma unroll
        for (int s = 0; s < 10; ++s) best[s] = ~0ULL;
        int x0 = max(0, cx - C), x1 = min(GRID - 1, cx + C);
        int y0 = max(0, cy - C), y1 = min(GRID - 1, cy + C);
        for (int yy = y0; yy <= y1; ++yy) {
            int s = cellStart[yy * GRID + x0];
            int e = cellStart[yy * GRID + x1 + 1];
            for (int t = s + sub; t < e; t += LPR) {
                float4 c = sxyz[t];
                float d2  = __fsub_rn(__fadd_rn(sqi, c.z),
                                      __fmul_rn(2.0f, fmaf(yi, c.y, __fmul_rn(xi, c.x))));
                float dst = __fsqrt_rn(fmaxf(d2, 0.0f));
                unsigned long long key =
                    ((unsigned long long)__float_as_uint(dst) << 32)
                    | (unsigned int)__float_as_int(c.w);
                if (key < best[9]) {
                    best[9] = key;
#pragma unroll
                    for (int ss = 9; ss >= 1; --ss) {
                        unsigned long long a = best[ss - 1], b = best[ss];
                        unsigned long long lo = a < b ? a : b;
                        unsigned long long hi = a < b ? b : a;
                        best[ss - 1] = lo;
                        best[ss]     = hi;
                    }
                }
            }
        }
        // merge LPR sorted lists: 10 rounds of head-min; winner pops its head
#pragma unroll
        for (int r = 0; r < 10; ++r) {
            unsigned long long mn = best[0];
#pragma unroll
            for (int off = 1; off < LPR; off <<= 1) {
                unsigned long long o = __shfl_xor(mn, off, 64);
                mn = (o < mn) ? o : mn;
            }
            if (best[0] == mn) {
#pragma unroll
                for (int ss = 0; ss < 9; ++ss) best[ss] = best[ss + 1];
                best[9] = ~0ULL;
            }
            merged[r] = mn;
        }
        bool done = false;
        if (merged[9] != ~0ULL) {
            float d9 = __uint_as_float((unsigned int)(merged[9] >> 32));
            // unscanned points are >= C*CELLW away; 1e-3 >> np-vs-ours dist dev
            if (d9 + 1.0e-3f <= (float)C * CELLW) done = true;
        }
        if (done || C >= GRID) break;
        C <<= 1; if (C > GRID) C = GRID;
    }

    if (sub == 0) {
        unsigned long long* o = chosen_ws + (size_t)row * 10;
#pragma unroll
        for (int r = 0; r < 10; ++r) o[r] = merged[r];
    }
}

// Phase 2 (fused, wave-per-row): slot-batched loads (10 independent float4
// loads per dim-chunk), p/q in registers, one butterfly pass per row, then
// the same wave runs blend + MLP. No LDS, no __syncthreads, no idle waves.
__global__ __launch_bounds__(256) void gather_final_kernel(
    const float* __restrict__ h0,
    const float* __restrict__ coords,
    const unsigned long long* __restrict__ chosen_ws,
    const float4* __restrict__ sxyz,
    const float* __restrict__ W1, const float* __restrict__ b1,
    const float* __restrict__ W2, const float* __restrict__ b2,
    float* __restrict__ out) {

    const int wid  = threadIdx.x >> 6;
    const int lane = threadIdx.x & 63;
    const int bid  = blockIdx.x;
    const int grp  = (bid & 7) * (gridDim.x / 8) + (bid >> 3);  // XCD-chunked
    const int g    = grp * 4 + wid;                             // sorted position
    const int row  = __float_as_int(sxyz[g].w);

    const unsigned long long* ch = chosen_ws + (size_t)row * 10;
    unsigned long long chosen[10];
    int jidx[10];
#pragma unroll
    for (int r = 0; r < 10; ++r) {
        chosen[r] = ch[r];
        jidx[r]   = (int)(chosen[r] & 0xFFFFFFFFu);
    }

    const float4* hi = (const float4*)(h0 + (size_t)row * DIM);

    float p[11];    // p[10] = self dot (a.a)
    float q[10];
#pragma unroll
    for (int s = 0; s < 11; ++s) p[s] = 0.f;
#pragma unroll
    for (int s = 0; s < 10; ++s) q[s] = 0.f;

    for (int t = 0; t < 4; ++t) {
        float4 av = hi[lane + 64 * t];
        p[10] += av.x * av.x + av.y * av.y + av.z * av.z + av.w * av.w;
#pragma unroll
        for (int s = 0; s < 10; ++s) {
            float4 b = ((const float4*)(h0 + (size_t)jidx[s] * DIM))[lane + 64 * t];
            p[s] += av.x * b.x + av.y * b.y + av.z * b.z + av.w * b.w;
            q[s] += b.x * b.x + b.y * b.y + b.z * b.z + b.w * b.w;
        }
    }

    // one butterfly pass per row (all lanes end with the sums)
#pragma unroll
    for (int s = 0; s < 11; ++s) {
        float v = p[s];
#pragma unroll
        for (int off = 1; off < 64; off <<= 1) v += __shfl_xor(v, off, 64);
        p[s] = v;
    }
#pragma unroll
    for (int s = 0; s < 10; ++s) {
        float v = q[s];
#pragma unroll
        for (int off = 1; off < 64; off <<= 1) v += __shfl_xor(v, off, 64);
        q[s] = v;
    }

    // ---- blend flags + sim/sw + MLP (verbatim logic from R5-R10) ----
    const float2 ci = ((const float2*)coords)[row];
    const float xi = ci.x, yi = ci.y;
    const float sqi = __fadd_rn(__fmul_rn(xi, xi), __fmul_rn(yi, yi));

    auto clamped_d2 = [&](unsigned long long key) -> float {
        int j = (int)(key & 0xFFFFFFFFu);
        float2 cj = ((const float2*)coords)[j];
        return fmaxf(np_d2(xi, yi, sqi, cj.x, cj.y), 0.0f);
    };
    const float m0 = clamped_d2(chosen[0]);
    const float m1 = clamped_d2(chosen[1]);
    const float m2 = clamped_d2(chosen[2]);
    const float m8 = clamped_d2(chosen[8]);
    const float m9 = clamped_d2(chosen[9]);

    const float WIN = 2.0e-6f;
    const bool fpair = (m1 - m0) <= WIN;
    const bool ftri  = fpair && ((m2 - m0) <= WIN);
    const bool f89   = (m9 - m8) <= WIN;

    float wd[3];
    wd[0] = ftri ? (1.f / 3.f) : (fpair ? 0.5f : 1.0f);
    wd[1] = ftri ? (1.f / 3.f) : (fpair ? 0.5f : 0.0f);
    wd[2] = ftri ? (1.f / 3.f) : 0.0f;
    const float wc0 = f89 ? 0.5f : 1.0f;
    const float wc1 = f89 ? 0.5f : 0.0f;

    const float ni = fmaxf(sqrtf(p[10]), 1e-8f);

    float sim[10], sw[10];
#pragma unroll
    for (int r = 0; r < 10; ++r) {
        float dst = __uint_as_float((unsigned int)(chosen[r] >> 32));
        float nj  = fmaxf(sqrtf(q[r]), 1e-8f);
        sim[r] = p[r] / (ni * nj);
        sw[r]  = expf(__fdiv_rn(-dst, 0.05f));
    }

    float Ssim = 0.f, Ssw = 0.f;
#pragma unroll
    for (int r = 0; r < 9; ++r) { Ssim += sim[r]; Ssw += sw[r]; }

    const float w1a = W1[lane], w1b = W1[64 + lane];
    const float b1l = b1[lane], w2l = W2[lane], b2s = b2[0];

    float outacc = 0.f;
#pragma unroll
    for (int d = 0; d < 3; ++d) {
#pragma unroll
        for (int c = 0; c < 2; ++c) {
            float wgt = wd[d] * (c ? wc1 : wc0);
            float simsum = Ssim - sim[d] + (c ? (sim[9] - sim[8]) : 0.f);
            float swsum  = Ssw  - sw[d]  + (c ? (sw[9]  - sw[8])  : 0.f);
            float di0 = simsum * 0.125f;
            float di1 = swsum  * 0.125f;
            float hm = fmaxf(di0 * w1a + di1 * w1b + b1l, 0.f);
            float v  = hm * w2l;
#pragma unroll
            for (int off = 1; off < 64; off <<= 1) v += __shfl_xor(v, off, 64);
            float z = v + b2s;
            outacc += wgt * (1.f / (1.f + expf(-z)));
        }
    }

    if (lane == 0) out[row] = outacc;
}

extern "C" void kernel_launch(void* const* d_in, const int* in_sizes, int n_in,
                              void* d_out, int out_size, void* d_ws, size_t ws_size,
                              hipStream_t stream) {
    const float* h0     = (const float*)d_in[0];
    const float* coords = (const float*)d_in[1];
    const float* W1     = (const float*)d_in[2];
    const float* b1     = (const float*)d_in[3];
    const float* W2     = (const float*)d_in[4];
    const float* b2     = (const float*)d_in[5];
    float* out = (float*)d_out;

    // ws layout
    char* ws = (char*)d_ws;
    unsigned long long* chosen_ws = (unsigned long long*)(ws);    // 655360 B
    float4* sxyz      = (float4*)(ws + 1015808);                  // 131072 B (16B aligned)
    int*    cellStart = (int*)(ws + 1146880);                     //  16388 B

    build_grid_kernel  <<<1, 1024, 0, stream>>>(coords, cellStart, sxyz);
    knn_kernel         <<<NROWS * LPR / 256, 256, 0, stream>>>(cellStart, sxyz, chosen_ws);
    gather_final_kernel<<<NROWS / 4, 256, 0, stream>>>(h0, coords, chosen_ws, sxyz,
                                                       W1, b1, W2, b2, out);
}